// Round 6
// baseline (1537.817 us; speedup 1.0000x reference)
//
#include <hip/hip_runtime.h>
#include <hip/hip_bf16.h>

// GraphEncoder: NNConv (edge-MLP 16->256->1024->1024 + einsum + scatter) + 3x GINConv.
// R13: 1509us. gemm256p 124.7us = 734 TF, MfmaUtil 30.6, VALUBusy 27(!), conflicts 0.
// Per-phase ledger: 1751 cyc vs m201's 824 at same schedule skeleton; the anomaly is
// VALUBusy ~470 cyc/phase with no legitimate VALU job -> at the 128-VGPR cap the
// compiler rematerializes swizzled LDS addrs + 64-bit stage addrs every phase.
// R14: address-folding rewrite of gemm256p:
//  - swizzle is separable: byte = laneBase(kk) + (QM*4+mi)*2048 -> 8 precomputed
//    lane-base pointers, ALL ds_read_b128 use compile-time immediate offsets.
//  - staging: addr = G + scalar(rbase+ck*8)*K + kt*64 + laneInvariant; per-lane
//    clamp only on block-uniform A-tail branch.
//  - template-exact phase: {reads; stage; [vmcnt(4) @ph4/8]; barrier; setprio+
//    16 MFMA+setprio; barrier}. Double barrier makes stage-pre-barrier WAR-safe.
//  - GIN g2 switched to gemm256p (K=256, N=256: 200-block single round).

#define NN 50000
#define EE 200000

typedef unsigned short u16;
typedef __attribute__((ext_vector_type(8))) short frag8;
typedef __attribute__((ext_vector_type(4))) float f32x4;

__device__ __forceinline__ float bf2f(u16 u) {
    union { unsigned int i; float f; } v; v.i = ((unsigned int)u) << 16; return v.f;
}
__device__ __forceinline__ u16 f2bf(float f) {
    union { float f; unsigned int i; } v; v.f = f;
    return (u16)((v.i + 0x7fffu + ((v.i >> 16) & 1u)) >> 16);
}
__device__ __forceinline__ float eluf(float v) {
    return v > 0.f ? v : __expf(v) - 1.f;
}

// ---------------- float dtype probe: fp32-as-bf16 shows crazy exponents ----------------
__global__ void probe_f32(const u16* __restrict__ raw, int* __restrict__ cnt) {
    int t = threadIdx.x;  // single block of 256
    int c = 0;
    for (int j = t; j < 1024; j += 256) {
        unsigned e = (raw[j] >> 7) & 0xFF;
        if (e >= 0xBF) c++;   // |v| >= 2^64: never in genuine N(0,1)-ish bf16 data
    }
    if (c) atomicAdd(cnt, c);
}
// dst bf16 <- src (fp32 if *cnt>=8 else bf16 passthrough)
__global__ void cvt_bf16(const void* __restrict__ src, u16* __restrict__ dst, long n,
                         const int* __restrict__ cnt) {
    long i = (long)blockIdx.x * 256 + threadIdx.x;
    if (i >= n) return;
    if (*cnt >= 8) dst[i] = f2bf(((const float*)src)[i]);
    else           dst[i] = ((const u16*)src)[i];
}

// ---------------- edge_index layout probe + conversion ----------------
__global__ void detect_idx64(const unsigned long long* __restrict__ p, int* __restrict__ flag) {
    long t = (long)blockIdx.x * 256 + threadIdx.x;
    if (t < EE) {
        unsigned long long v = p[t];
        if (v >> 31) atomicOr(flag, 1);   // int32-packed pairs have high bits set
    }
}
__global__ void convert_idx(const void* __restrict__ raw, const int* __restrict__ flag,
                            int* __restrict__ s_out, int* __restrict__ d_out) {
    long t = (long)blockIdx.x * 256 + threadIdx.x;
    if (t >= EE) return;
    if (*flag) {  // int32 layout
        const int* q = (const int*)raw;
        s_out[t] = q[t];
        d_out[t] = q[EE + t];
    } else {      // int64 layout
        const long long* q = (const long long*)raw;
        s_out[t] = (int)q[t];
        d_out[t] = (int)q[EE + t];
    }
}

// ---------------- generic bf16 transpose [K,N] -> [N,K] ----------------
__global__ void transpose_bf16(const u16* __restrict__ in, u16* __restrict__ out, int K, int N) {
    long idx = (long)blockIdx.x * 256 + threadIdx.x;
    if (idx < (long)K * N) {
        int k = (int)(idx / N);
        int n = (int)(idx % N);
        out[(long)n * K + k] = in[idx];
    }
}

// ---------------- edge MLP layer 1: h1 = ELU(attr @ W1 + b1), K=16, N=256 ----------------
__global__ void edge_mlp1(const u16* __restrict__ attr, const u16* __restrict__ w1,
                          const u16* __restrict__ b1, u16* __restrict__ h1, int ce) {
    __shared__ u16 sa[256];
    const int t = threadIdx.x;
    const int e0 = blockIdx.x * 16;
    const int cnt = min(16, ce - e0);
    sa[t] = (t < cnt * 16) ? attr[(long)e0 * 16 + t] : (u16)0;
    float w[16];
    #pragma unroll
    for (int i = 0; i < 16; ++i) w[i] = bf2f(w1[i * 256 + t]);
    const float bb = bf2f(b1[t]);
    __syncthreads();
    for (int e = 0; e < cnt; ++e) {
        float v = bb;
        #pragma unroll
        for (int i = 0; i < 16; ++i) v += bf2f(sa[e * 16 + i]) * w[i];
        h1[(long)(e0 + e) * 256 + t] = f2bf(eluf(v));
    }
}

// ---- stage 128x32 bf16 tile via global_load_lds (old 128^2 path, GIN g1) ----
__device__ __forceinline__ void stage_tile(const u16* g, long row_base, long max_row,
                                           int kstride, int k0, u16* s, int t) {
    int wave = t >> 6;
    #pragma unroll
    for (int j = 0; j < 2; ++j) {
        int c = t + 256 * j;                 // chunk id 0..511 (16B each)
        long r = row_base + (c >> 2);        // 4 chunks per 32-elem row
        if (r > max_row) r = max_row;        // tail clamp (masked at C store)
        const u16* gp = g + r * (long)kstride + k0 + (c & 3) * 8;
        __builtin_amdgcn_global_load_lds(
            (__attribute__((address_space(1))) void*)(void*)gp,
            (__attribute__((address_space(3))) void*)((char*)s + wave * 1024 + j * 4096),
            16, 0, 0);                       // HW writes LDS at base + lane*16
    }
}

// C = ELU(A[M,K] @ BT[N,K]^T + bias), bf16 out. N mult of 128, K mult of 32.
// XCD-swizzled 1D grid. Kept for GIN g1 (K=64).
__global__ __launch_bounds__(256)
void gemm_bt_bias_elu(const u16* __restrict__ A, const u16* __restrict__ BT,
                      const u16* __restrict__ bias, u16* __restrict__ C,
                      int M, int K, int N, int mpx, int lognt) {
    const int bid = blockIdx.x;
    const int xcd = bid & 7;
    const int j = bid >> 3;
    const int m_idx = xcd * mpx + (j >> lognt);
    const int n_idx = j & ((1 << lognt) - 1);
    const int num_m = (M + 127) >> 7;
    if (m_idx >= num_m) return;              // block-uniform; before any barrier

    __shared__ __align__(16) u16 sA[128 * 32];
    __shared__ __align__(16) u16 sB[128 * 32];
    const int t = threadIdx.x;
    const int lane = t & 63;
    const int wave = t >> 6;
    const int wr = wave >> 1, wc = wave & 1;
    const int quad = lane >> 4, l16 = lane & 15;
    const long m0 = (long)m_idx * 128;
    const int n0 = n_idx * 128;

    f32x4 acc[4][4];
    const f32x4 z4 = {0.f, 0.f, 0.f, 0.f};
    #pragma unroll
    for (int mi = 0; mi < 4; ++mi)
        #pragma unroll
        for (int ni = 0; ni < 4; ++ni)
            acc[mi][ni] = z4;

    for (int k0 = 0; k0 < K; k0 += 32) {
        stage_tile(A, m0, (long)M - 1, K, k0, sA, t);
        stage_tile(BT, n0, (long)N - 1, K, k0, sB, t);
        __syncthreads();
        frag8 af[4], bfv[4];
        #pragma unroll
        for (int mi = 0; mi < 4; ++mi)
            af[mi] = *(const frag8*)(sA + (wr * 64 + mi * 16 + l16) * 32 + quad * 8);
        #pragma unroll
        for (int ni = 0; ni < 4; ++ni)
            bfv[ni] = *(const frag8*)(sB + (wc * 64 + ni * 16 + l16) * 32 + quad * 8);
        #pragma unroll
        for (int mi = 0; mi < 4; ++mi)
            #pragma unroll
            for (int ni = 0; ni < 4; ++ni)
                acc[mi][ni] = __builtin_amdgcn_mfma_f32_16x16x32_bf16(af[mi], bfv[ni], acc[mi][ni], 0, 0, 0);
        __syncthreads();
    }

    #pragma unroll
    for (int mi = 0; mi < 4; ++mi) {
        #pragma unroll
        for (int r = 0; r < 4; ++r) {
            long row = m0 + wr * 64 + mi * 16 + quad * 4 + r;  // C/D: row = quad*4+reg
            if (row < M) {
                #pragma unroll
                for (int ni = 0; ni < 4; ++ni) {
                    int col = n0 + wc * 64 + ni * 16 + l16;    // C/D: col = lane&15
                    float v = acc[mi][ni][r] + bf2f(bias[col]);
                    C[row * (long)N + col] = f2bf(eluf(v));
                }
            }
        }
    }
}

// ---------------- R14: 8-phase 256x256 GEMM, BK=64, folded addressing ----------------
// 512 thr = 8 waves (2M x 4N), per-wave out 128x64. LDS 128KB = buf{0,1} x
// {A0,A1,B0,B1} x 16KB regions; region = 128 rows x 64 k, row = 128B, swizzle:
// LDS[row][s] holds global 16B-slot s^(row&7). The swizzle is SEPARABLE:
// read byte = laneBase(kk) + (subtile)*2048, laneBase = l16*128 +
// ((quad^(l16&3))<<4) + (((l16>>2)&1 ^ kk)<<6)  -> 8 precomputed base pointers,
// every ds_read_b128 gets a compile-time immediate offset (no per-phase VALU).
// Phase: {reads; stage 1 region; [vmcnt(4) @ph4/8]; barrier; setprio; 16 MFMA;
// setprio; barrier}. Stage-pre-barrier is WAR-safe under the double barrier:
// region R's stage at phase p issues >= 2 barriers after all waves' last reads
// of R retired. Confirm side: reads of tile T occur >=1 barrier after the
// vmcnt(4) that retires T's loads (stage order per iter:
// ph1 Y.A0<-t1, ph2 Y.A1<-t1, ph3 X.B0<-t2, ph4 X.B1<-t2 +vmcnt(4) [12 out
// -> retires through Y.A1], ph5 X.A0<-t2, ph6 X.A1<-t2, ph7 Y.B0<-t3,
// ph8 Y.B1<-t3 +vmcnt(4) [retires through X.A1]). Last iter clamps -> dead
// re-stages of consumed regions, masked at C store.

#define QPHASE(PA0, PA1, PB0, PB1, QM, QN, LDA, LDB, VMW, STREG, SG, SRB, SRM, SCL, SKT) \
  do {                                                                           \
    if (LDA) {                                                                   \
      _Pragma("unroll")                                                          \
      for (int mi = 0; mi < 4; ++mi) {                                           \
        av[mi][0] = *(const frag8*)((PA0) + ((QM) * 4 + mi) * 2048);             \
        av[mi][1] = *(const frag8*)((PA1) + ((QM) * 4 + mi) * 2048);             \
      }                                                                          \
    }                                                                            \
    if ((LDB) >= 0) {                                                            \
      _Pragma("unroll")                                                          \
      for (int ni = 0; ni < 2; ++ni) {                                           \
        bv[(LDB) & 1][ni][0] = *(const frag8*)((PB0) + (((LDB) & 1) * 2 + ni) * 2048); \
        bv[(LDB) & 1][ni][1] = *(const frag8*)((PB1) + (((LDB) & 1) * 2 + ni) * 2048); \
      }                                                                          \
    }                                                                            \
    stage((STREG), (SG), (SRB), (SRM), (SKT), (SCL));                            \
    if (VMW) asm volatile("s_waitcnt vmcnt(4)" ::: "memory");                    \
    __builtin_amdgcn_s_barrier();                                                \
    __builtin_amdgcn_s_setprio(1);                                               \
    _Pragma("unroll")                                                            \
    for (int kk = 0; kk < 2; ++kk) {                                             \
      _Pragma("unroll")                                                          \
      for (int mi = 0; mi < 4; ++mi) {                                           \
        _Pragma("unroll")                                                        \
        for (int ni = 0; ni < 2; ++ni) {                                         \
          acc[(QM) * 4 + mi][(QN) * 2 + ni] =                                    \
              __builtin_amdgcn_mfma_f32_16x16x32_bf16(                           \
                  av[mi][kk], bv[(QN)][ni][kk],                                  \
                  acc[(QM) * 4 + mi][(QN) * 2 + ni], 0, 0, 0);                   \
        }                                                                        \
      }                                                                          \
    }                                                                            \
    __builtin_amdgcn_s_setprio(0);                                               \
    __builtin_amdgcn_s_barrier();                                                \
  } while (0)

__global__ __launch_bounds__(512, 2)
void gemm256p(const u16* __restrict__ A, const u16* __restrict__ BT,
              const u16* __restrict__ bias, u16* __restrict__ C,
              int M, int K, int N, int mpx, int lognt) {
    const int bid = blockIdx.x;
    const int xcd = bid & 7;
    const int j = bid >> 3;
    const int m_idx = xcd * mpx + (j >> lognt);
    const int n_idx = j & ((1 << lognt) - 1);
    const int num_m = (M + 255) >> 8;
    if (m_idx >= num_m) return;              // block-uniform; before any barrier

    __shared__ __align__(16) u16 lds[2][4][8192];  // [buf][A0,A1,B0,B1][16KB]
    const int t = threadIdx.x;
    const int lane = t & 63;
    const int wave = t >> 6;          // 0..7
    const int wm = wave >> 2;         // 0..1 : M half (128 rows)
    const int wn = wave & 3;          // 0..3 : N quarter (64 cols)
    const int quad = lane >> 4, l16 = lane & 15;
    const long m0 = (long)m_idx * 256;
    const long n0 = (long)n_idx * 256;

    // ---- folded LDS read bases (separable swizzle) ----
    const int aoff0 = l16 * 128 + ((quad ^ (l16 & 3)) << 4) + (((l16 >> 2) & 1) << 6);
    const int aoff1 = aoff0 ^ 64;                       // kk=1 flips byte-bit 6
    const int bex = (wn & 1) * 8192;
    const char* pAX0 = (const char*)&lds[0][wm][0] + aoff0;
    const char* pAX1 = (const char*)&lds[0][wm][0] + aoff1;
    const char* pAY0 = (const char*)&lds[1][wm][0] + aoff0;
    const char* pAY1 = (const char*)&lds[1][wm][0] + aoff1;
    const char* pBX0 = (const char*)&lds[0][2 + (wn >> 1)][0] + aoff0 + bex;
    const char* pBX1 = (const char*)&lds[0][2 + (wn >> 1)][0] + aoff1 + bex;
    const char* pBY0 = (const char*)&lds[1][2 + (wn >> 1)][0] + aoff0 + bex;
    const char* pBY1 = (const char*)&lds[1][2 + (wn >> 1)][0] + aoff1 + bex;

    // ---- staging: chunk ck = wave*2+jj covers 8 rows (1KB); lane -> row
    // ck*8+(lane>>3), global 16B-slot pre-swizzled g=(lane&7)^((lane>>3)&7)
    // so the swizzled read finds global slot s at LDS slot s^(row&7). ----
    const int gslot = (((lane & 7) ^ ((lane >> 3) & 7)) << 3);  // elem offset
    const int lane_row = lane >> 3;                             // 0..7
    const long lane_go = (long)lane_row * K + gslot;            // lane-invariant

    auto stage = [&](u16* sreg, const u16* G, long rbase, long rmax, int kt, bool cl) {
        #pragma unroll
        for (int jj = 0; jj < 2; ++jj) {
            const int ck = wave * 2 + jj;
            const u16* gp;
            if (!cl) {
                gp = G + (rbase + ck * 8) * (long)K + ((long)kt << 6) + lane_go;
            } else {
                long r = rbase + ck * 8 + lane_row;
                if (r > rmax) r = rmax;      // tail clamp, masked at C store
                gp = G + r * (long)K + ((long)kt << 6) + gslot;
            }
            __builtin_amdgcn_global_load_lds(
                (__attribute__((address_space(1))) void*)(void*)gp,
                (__attribute__((address_space(3))) void*)((char*)sreg + ck * 1024),
                16, 0, 0);
        }
    };

    f32x4 acc[8][4];
    const f32x4 z4 = {0.f, 0.f, 0.f, 0.f};
    #pragma unroll
    for (int mi = 0; mi < 8; ++mi)
        #pragma unroll
        for (int ni = 0; ni < 4; ++ni)
            acc[mi][ni] = z4;
    frag8 av[4][2];        // current A quadrant (4 m-subtiles x 2 kk)
    frag8 bv[2][2][2];     // both B sets [qn][ni][kk]

    const int ntk = K >> 6;          // K multiple of 128 -> ntk even
    const int niter = ntk >> 1;
    const long MM = (long)M - 1, NMX = (long)N - 1;
    const bool aclamp = (m0 + 255) > MM;     // block-uniform

    // prologue: X <- tile0 (8 loads, oldest), Y.B <- tile1 (4 loads).
    stage(&lds[0][2][0], BT, n0,       NMX, 0, false);
    stage(&lds[0][3][0], BT, n0 + 128, NMX, 0, false);
    stage(&lds[0][0][0], A,  m0,       MM,  0, aclamp);
    stage(&lds[0][1][0], A,  m0 + 128, MM,  0, aclamp);
    stage(&lds[1][2][0], BT, n0,       NMX, 1, false);
    stage(&lds[1][3][0], BT, n0 + 128, NMX, 1, false);
    asm volatile("s_waitcnt vmcnt(4)" ::: "memory");   // tile0's 8 loads landed
    __builtin_amdgcn_s_barrier();

    for (int it = 0; it < niter; ++it) {
        const int t1k = 2 * it + 1;
        int t2k = 2 * it + 2; if (t2k > ntk - 1) t2k = ntk - 1;
        int t3k = 2 * it + 3; if (t3k > ntk - 1) t3k = ntk - 1;

        QPHASE(pAX0, pAX1, pBX0, pBX1, 0, 0, 1,  0, 0, &lds[1][0][0], A,  m0,       MM,  aclamp, t1k);
        QPHASE(pAX0, pAX1, pBX0, pBX1, 0, 1, 0,  1, 0, &lds[1][1][0], A,  m0 + 128, MM,  aclamp, t1k);
        QPHASE(pAX0, pAX1, pBX0, pBX1, 1, 0, 1, -1, 0, &lds[0][2][0], BT, n0,       NMX, false,  t2k);
        QPHASE(pAX0, pAX1, pBX0, pBX1, 1, 1, 0, -1, 1, &lds[0][3][0], BT, n0 + 128, NMX, false,  t2k);
        QPHASE(pAY0, pAY1, pBY0, pBY1, 0, 0, 1,  0, 0, &lds[0][0][0], A,  m0,       MM,  aclamp, t2k);
        QPHASE(pAY0, pAY1, pBY0, pBY1, 0, 1, 0,  1, 0, &lds[0][1][0], A,  m0 + 128, MM,  aclamp, t2k);
        QPHASE(pAY0, pAY1, pBY0, pBY1, 1, 0, 1, -1, 0, &lds[1][2][0], BT, n0,       NMX, false,  t3k);
        QPHASE(pAY0, pAY1, pBY0, pBY1, 1, 1, 0, -1, 1, &lds[1][3][0], BT, n0 + 128, NMX, false,  t3k);
    }
    asm volatile("s_waitcnt vmcnt(0)" ::: "memory");   // drain leftover stages

    #pragma unroll
    for (int mi = 0; mi < 8; ++mi) {
        #pragma unroll
        for (int r = 0; r < 4; ++r) {
            long row = m0 + wm * 128 + mi * 16 + quad * 4 + r;   // C/D: row = quad*4+reg
            if (row < M) {
                #pragma unroll
                for (int ni = 0; ni < 4; ++ni) {
                    long col = n0 + wn * 64 + ni * 16 + l16;     // C/D: col = lane&15
                    float v = acc[mi][ni][r] + bf2f(bias[col]);
                    C[row * (long)N + col] = f2bf(eluf(v));
                }
            }
        }
    }
}

// C[M,64] fp32 = A[M,K] @ BT[64,K]^T + bias (no ELU). M-tile 256, N=64, K mult of 32.
__global__ __launch_bounds__(256)
void gemm_bt_f32(const u16* __restrict__ A, const u16* __restrict__ BT,
                 const u16* __restrict__ bias, float* __restrict__ C,
                 int M, int K) {
    __shared__ __align__(16) u16 sA[256 * 32];
    __shared__ __align__(16) u16 sB[64 * 32];
    const int t = threadIdx.x;
    const int lane = t & 63;
    const int wave = t >> 6;
    const int quad = lane >> 4, l16 = lane & 15;
    const long m0 = (long)blockIdx.x * 256;

    f32x4 acc[4][4];
    const f32x4 z4 = {0.f, 0.f, 0.f, 0.f};
    #pragma unroll
    for (int mi = 0; mi < 4; ++mi)
        #pragma unroll
        for (int ni = 0; ni < 4; ++ni)
            acc[mi][ni] = z4;

    for (int k0 = 0; k0 < K; k0 += 32) {
        #pragma unroll
        for (int j = 0; j < 4; ++j) {
            int c = t + 256 * j;
            long r = m0 + (c >> 2);
            if (r > (long)M - 1) r = (long)M - 1;
            const u16* gp = A + r * (long)K + k0 + (c & 3) * 8;
            __builtin_amdgcn_global_load_lds(
                (__attribute__((address_space(1))) void*)(void*)gp,
                (__attribute__((address_space(3))) void*)((char*)sA + wave * 1024 + j * 4096),
                16, 0, 0);
        }
        {
            int c = t;
            const u16* gp = BT + (long)(c >> 2) * K + k0 + (c & 3) * 8;
            __builtin_amdgcn_global_load_lds(
                (__attribute__((address_space(1))) void*)(void*)gp,
                (__attribute__((address_space(3))) void*)((char*)sB + wave * 1024),
                16, 0, 0);
        }
        __syncthreads();
        frag8 af[4], bfv[4];
        #pragma unroll
        for (int mi = 0; mi < 4; ++mi)
            af[mi] = *(const frag8*)(sA + (wave * 64 + mi * 16 + l16) * 32 + quad * 8);
        #pragma unroll
        for (int ni = 0; ni < 4; ++ni)
            bfv[ni] = *(const frag8*)(sB + (ni * 16 + l16) * 32 + quad * 8);
        #pragma unroll
        for (int mi = 0; mi < 4; ++mi)
            #pragma unroll
            for (int ni = 0; ni < 4; ++ni)
                acc[mi][ni] = __builtin_amdgcn_mfma_f32_16x16x32_bf16(af[mi], bfv[ni], acc[mi][ni], 0, 0, 0);
        __syncthreads();
    }

    #pragma unroll
    for (int mi = 0; mi < 4; ++mi) {
        #pragma unroll
        for (int r = 0; r < 4; ++r) {
            long row = m0 + wave * 64 + mi * 16 + quad * 4 + r;
            if (row < M) {
                #pragma unroll
                for (int ni = 0; ni < 4; ++ni) {
                    int col = ni * 16 + l16;
                    C[row * 64 + col] = acc[mi][ni][r] + bf2f(bias[col]);
                }
            }
        }
    }
}

// msg[e,o] = sum_i x[src[e],i] * we[e, i*64+o]; atomicAdd into agg[dst[e],o]
__global__ void nnconv_msg(const u16* __restrict__ we, const u16* __restrict__ x,
                           const int* __restrict__ src, const int* __restrict__ dst,
                           float* __restrict__ agg, int ce) {
    long idx = (long)blockIdx.x * 256 + threadIdx.x;
    if (idx >= (long)ce * 64) return;
    int o = (int)(idx & 63);
    long e = idx >> 6;
    const u16* wr = we + e * 1024;
    const u16* xr = x + (long)src[e] * 16;
    float v = 0.f;
    #pragma unroll
    for (int i = 0; i < 16; ++i)
        v += bf2f(xr[i]) * bf2f(wr[i * 64 + o]);
    atomicAdd(&agg[(long)dst[e] * 64 + o], v);
}

// ---- x_cur(emb0) = x @ root_w + root_b + agg (in-place on agg) ----
__global__ void add_root(const u16* __restrict__ x, const u16* __restrict__ rw,
                         const u16* __restrict__ rb, float* __restrict__ xcur) {
    long idx = (long)blockIdx.x * 256 + threadIdx.x;
    if (idx >= (long)NN * 64) return;
    int d = (int)(idx & 63);
    long n = idx >> 6;
    float v = bf2f(rb[d]);
    #pragma unroll
    for (int i = 0; i < 16; ++i)
        v += bf2f(x[n * 16 + i]) * bf2f(rw[i * 64 + d]);
    xcur[idx] += v;
}

__global__ void elu_bf16(const float* __restrict__ in, u16* __restrict__ o, long n) {
    long idx = (long)blockIdx.x * 256 + threadIdx.x;
    if (idx < n) o[idx] = f2bf(eluf(in[idx]));
}

__global__ void gin_scatter(const u16* __restrict__ xin, const int* __restrict__ src,
                            const int* __restrict__ dst, float* __restrict__ nbr) {
    long idx = (long)blockIdx.x * 256 + threadIdx.x;
    if (idx >= (long)EE * 64) return;
    int d = (int)(idx & 63);
    long e = idx >> 6;
    atomicAdd(&nbr[(long)dst[e] * 64 + d], bf2f(xin[(long)src[e] * 64 + d]));
}

__global__ void gin_combine(const u16* __restrict__ xin, const float* __restrict__ nbr,
                            u16* __restrict__ hin, long n) {
    long idx = (long)blockIdx.x * 256 + threadIdx.x;
    if (idx < n) hin[idx] = f2bf(bf2f(xin[idx]) + nbr[idx]);
}

// out[n,d,l] = emb_l[n*64+d] -- one float4 per (n,d), fully coalesced
__global__ void write_out(const float* __restrict__ e0, const float* __restrict__ e1,
                          const float* __restrict__ e2, const float* __restrict__ e3,
                          float* __restrict__ out) {
    long idx = (long)blockIdx.x * 256 + threadIdx.x;
    if (idx >= (long)NN * 64) return;
    float4 v = {e0[idx], e1[idx], e2[idx], e3[idx]};
    *(float4*)(out + idx * 4) = v;
}

extern "C" void kernel_launch(void* const* d_in, const int* in_sizes, int n_in,
                              void* d_out, int out_size, void* d_ws, size_t ws_size,
                              hipStream_t stream) {
    (void)in_sizes; (void)n_in; (void)out_size;
    const void* eidx = d_in[1];
    float* out = (float*)d_out;   // reference output dtype = float32

    char* ws = (char*)d_ws;
    size_t off = 0;
    auto alloc = [&](size_t bytes) {
        char* p = ws + off;
        off += (bytes + 255) & ~(size_t)255;
        return p;
    };
    // ---- persistent ----
    int* src32 = (int*)alloc((size_t)EE * 4);
    int* dst32 = (int*)alloc((size_t)EE * 4);
    int* flag  = (int*)alloc(256);
    int* cnt   = (int*)alloc(256);
    const int cv_idx[16] = {0, 2, 3, 4, 5, 6, 7, 8, 9, 10, 11, 12, 13, 14, 15, 16};
    const long cv_n[16]  = {800000, 3200000, 4096, 256, 262144, 1024, 1048576, 1024,
                            1024, 64, 49152, 768, 196608, 768, 49152, 192};
    u16* cv[16];
    for (int i = 0; i < 16; ++i) cv[i] = (u16*)alloc((size_t)cv_n[i] * 2);
    u16 *xc = cv[0], *eac = cv[1], *w1c = cv[2], *b1c = cv[3], *w2c = cv[4], *b2c = cv[5],
        *w3c = cv[6], *b3c = cv[7], *rwc = cv[8], *rbc = cv[9],
        *g1c = cv[10], *gb1c = cv[11], *g2c = cv[12], *gb2c = cv[13], *g3c = cv[14], *gb3c = cv[15];
    u16* w2t = (u16*)alloc((size_t)1024 * 256 * 2);
    u16* w3t = (u16*)alloc((size_t)1024 * 1024 * 2);
    u16* g1t = (u16*)alloc((size_t)3 * 256 * 64 * 2);
    u16* g2t = (u16*)alloc((size_t)3 * 256 * 256 * 2);
    u16* g3t = (u16*)alloc((size_t)3 * 64 * 256 * 2);
    // per-layer node embeddings, fp32 [N,64]; emb[0] doubles as agg/x_cur
    float* emb[4];
    for (int l = 0; l < 4; ++l) emb[l] = (float*)alloc((size_t)NN * 64 * 4);
    float* agg = emb[0];
    char* scratch = (char*)alloc(0);
    size_t avail = (ws_size > off + 4096) ? (ws_size - off - 4096) : 0;

    // ---- NNConv edge-chunk: h1c (512 B/e) + h2c (2048 B/e) + wec (2048 B/e) ----
    long CE = (long)(avail / 4608) & ~127L;
    if (CE < 128) CE = 128;
    if (CE > 200064) CE = 200064;
    u16* h1c = (u16*)scratch;
    u16* h2c = (u16*)(scratch + (size_t)CE * 512);
    u16* wec = (u16*)(scratch + (size_t)CE * 2560);

    // ---- GIN node-chunk: nbr+xin fixed (19.2MB) + 1152 B/node ----
    long gin_fixed = (long)NN * 64 * 4 + (long)NN * 64 * 2;
    long gin_avail = (long)avail - gin_fixed;
    if (gin_avail < 0) gin_avail = 0;
    long CN = (gin_avail / 1152) & ~255L;
    if (CN < 256) CN = 256;
    if (CN > 50176) CN = 50176;
    float* nbr = (float*)scratch;
    u16* xin   = (u16*)(scratch + (size_t)NN * 64 * 4);
    u16* hin   = (u16*)(scratch + gin_fixed);
    u16* hg1   = hin + (size_t)CN * 64;
    u16* hg2   = hg1 + (size_t)CN * 256;

    auto cdiv = [](long a, long b) { return (unsigned)((a + b - 1) / b); };

    // dtype probe on x, then normalize all float inputs to bf16
    hipMemsetAsync(cnt, 0, 4, stream);
    probe_f32<<<1, 256, 0, stream>>>((const u16*)d_in[0], cnt);
    for (int i = 0; i < 16; ++i)
        cvt_bf16<<<cdiv(cv_n[i], 256), 256, 0, stream>>>(d_in[cv_idx[i]], cv[i], cv_n[i], cnt);

    // edge_index conversion (layout-robust)
    hipMemsetAsync(flag, 0, 4, stream);
    detect_idx64<<<cdiv(EE, 256), 256, 0, stream>>>((const unsigned long long*)eidx, flag);
    convert_idx<<<cdiv(EE, 256), 256, 0, stream>>>(eidx, flag, src32, dst32);

    // weight transposes [K,N] -> [N,K]
    transpose_bf16<<<cdiv(256 * 1024, 256), 256, 0, stream>>>(w2c, w2t, 256, 1024);
    transpose_bf16<<<cdiv(1024 * 1024, 256), 256, 0, stream>>>(w3c, w3t, 1024, 1024);
    for (int l = 0; l < 3; ++l) {
        transpose_bf16<<<cdiv(64 * 256, 256), 256, 0, stream>>>(g1c + l * 64 * 256, g1t + l * 256 * 64, 64, 256);
        transpose_bf16<<<cdiv(256 * 256, 256), 256, 0, stream>>>(g2c + l * 256 * 256, g2t + l * 256 * 256, 256, 256);
        transpose_bf16<<<cdiv(256 * 64, 256), 256, 0, stream>>>(g3c + l * 256 * 64, g3t + l * 64 * 256, 256, 64);
    }

    // ---- NNConv (edge-chunked) ----
    hipMemsetAsync(agg, 0, (size_t)NN * 64 * 4, stream);
    for (long e0 = 0; e0 < EE; e0 += CE) {
        int ce = (int)((EE - e0 < CE) ? (EE - e0) : CE);
        int mpx2 = cdiv(cdiv(ce, 256), 8);
        edge_mlp1<<<cdiv(ce, 16), 256, 0, stream>>>(eac + e0 * 16, w1c, b1c, h1c, ce);
        gemm256p<<<8 * mpx2 * 4, 512, 0, stream>>>(h1c, w2t, b2c, h2c, ce, 256, 1024, mpx2, 2);
        gemm256p<<<8 * mpx2 * 4, 512, 0, stream>>>(h2c, w3t, b3c, wec, ce, 1024, 1024, mpx2, 2);
        nnconv_msg<<<cdiv((long)ce * 64, 256), 256, 0, stream>>>(wec, xc, src32 + e0, dst32 + e0, agg, ce);
    }
    add_root<<<cdiv((long)NN * 64, 256), 256, 0, stream>>>(xc, rwc, rbc, agg);

    // ---- 3x GINConv (node-chunked MLP) ----
    for (int l = 0; l < 3; ++l) {
        elu_bf16<<<cdiv((long)NN * 64, 256), 256, 0, stream>>>(emb[l], xin, (long)NN * 64);
        hipMemsetAsync(nbr, 0, (size_t)NN * 64 * 4, stream);
        gin_scatter<<<cdiv((long)EE * 64, 256), 256, 0, stream>>>(xin, src32, dst32, nbr);
        for (long n0 = 0; n0 < NN; n0 += CN) {
            int cn = (int)((NN - n0 < CN) ? (NN - n0) : CN);
            int mpx = cdiv(cdiv(cn, 128), 8);
            int mpx2 = cdiv(cdiv(cn, 256), 8);
            gin_combine<<<cdiv((long)cn * 64, 256), 256, 0, stream>>>(xin + n0 * 64, nbr + n0 * 64, hin, (long)cn * 64);
            gemm_bt_bias_elu<<<8 * mpx * 2, 256, 0, stream>>>(hin, g1t + l * 256 * 64, gb1c + l * 256, hg1, cn, 64, 256, mpx, 1);
            gemm256p<<<8 * mpx2 * 1, 512, 0, stream>>>(hg1, g2t + l * 256 * 256, gb2c + l * 256, hg2, cn, 256, 256, mpx2, 0);
            gemm_bt_f32<<<cdiv(cn, 256), 256, 0, stream>>>(hg2, g3t + l * 64 * 256, gb3c + l * 64, emb[l + 1] + n0 * 64, cn, 256);
        }
    }
    write_out<<<cdiv((long)NN * 64, 256), 256, 0, stream>>>(emb[0], emb[1], emb[2], emb[3], out);
}